// Round 6
// baseline (263.398 us; speedup 1.0000x reference)
//
#include <hip/hip_runtime.h>
#include <hip/hip_fp16.h>

// Problem constants (from reference)
#define NN 100000
#define KK 32
#define DD 128
// remove = floor(32*0.45) = 14 -> keep sorted ranks [14,18), mean of 4

typedef _Float16 v8h __attribute__((ext_vector_type(8)));
typedef _Float16 v4h __attribute__((ext_vector_type(4)));
typedef _Float16 v2h __attribute__((ext_vector_type(2)));
typedef float    v4f __attribute__((ext_vector_type(4)));

#define LDH 136   // padded LDS row stride in f16 (128 + 8)

// h scratch layout: 8 channel-group slabs, hs[g][n][16] f16.
// slab g holds channels [16g, 16g+16); slab size = NN*32 B = 3.2 MB < 4 MiB L2.
#define SLAB_HALVES ((size_t)NN * 16)

// ---------------------------------------------------------------------------
// Kernel 1: h = x @ W^T in f16 via MFMA 16x16x32, writing slab layout.
// (unchanged; ~15 us, near memory floor)
// ---------------------------------------------------------------------------
__global__ __launch_bounds__(256)
void gemm_mfma_kernel(const float* __restrict__ x, const float* __restrict__ W,
                      _Float16* __restrict__ hs) {
    __shared__ _Float16 w_lds[DD * LDH];
    __shared__ _Float16 x_lds[128 * LDH];

    const int tid = threadIdx.x;
    const int block_row = blockIdx.x * 128;

    {
        const float4* ws = (const float4*)W;
        #pragma unroll
        for (int t = 0; t < 16; ++t) {
            const int fi = tid + 256 * t;
            const int r = fi >> 5, c4 = fi & 31;
            const float4 f = ws[fi];
            v4h p = { (_Float16)f.x, (_Float16)f.y, (_Float16)f.z, (_Float16)f.w };
            *(v4h*)&w_lds[r * LDH + c4 * 4] = p;
        }
    }
    {
        const float4* xs = (const float4*)x;
        #pragma unroll
        for (int t = 0; t < 16; ++t) {
            const int fi = tid + 256 * t;
            const int r = fi >> 5, c4 = fi & 31;
            const int gr = block_row + r;
            float4 f = make_float4(0.f, 0.f, 0.f, 0.f);
            if (gr < NN) f = xs[(size_t)gr * 32 + c4];
            v4h p = { (_Float16)f.x, (_Float16)f.y, (_Float16)f.z, (_Float16)f.w };
            *(v4h*)&x_lds[r * LDH + c4 * 4] = p;
        }
    }
    __syncthreads();

    const int wv   = tid >> 6;
    const int lane = tid & 63;
    const int m    = lane & 15;
    const int quad = lane >> 4;

    const v4f zero = {0.f, 0.f, 0.f, 0.f};
    v4f acc[2][8];
    #pragma unroll
    for (int nt = 0; nt < 2; ++nt)
        #pragma unroll
        for (int ot = 0; ot < 8; ++ot) acc[nt][ot] = zero;

    #pragma unroll
    for (int ks = 0; ks < 4; ++ks) {
        const int kb = ks * 32 + quad * 8;
        const v8h xf0 = *(const v8h*)&x_lds[(wv * 32 + m) * LDH + kb];
        const v8h xf1 = *(const v8h*)&x_lds[(wv * 32 + 16 + m) * LDH + kb];
        #pragma unroll
        for (int ot = 0; ot < 8; ++ot) {
            const v8h wf = *(const v8h*)&w_lds[(ot * 16 + m) * LDH + kb];
            acc[0][ot] = __builtin_amdgcn_mfma_f32_16x16x32_f16(wf, xf0, acc[0][ot], 0, 0, 0);
            acc[1][ot] = __builtin_amdgcn_mfma_f32_16x16x32_f16(wf, xf1, acc[1][ot], 0, 0, 0);
        }
    }

    #pragma unroll
    for (int nt = 0; nt < 2; ++nt) {
        const int xr = block_row + wv * 32 + nt * 16 + m;
        if (xr < NN) {
            #pragma unroll
            for (int ot = 0; ot < 8; ++ot) {
                const v4f a = acc[nt][ot];
                v4h p = { (_Float16)a.x, (_Float16)a.y, (_Float16)a.z, (_Float16)a.w };
                *(v4h*)&hs[(size_t)ot * SLAB_HALVES + (size_t)xr * 16 + quad * 4] = p;
            }
        }
    }
}

// ---------------------------------------------------------------------------
// Compile-time Batcher odd-even mergesort network for 16 elements (63 CEs).
// ---------------------------------------------------------------------------
struct CEp { signed char a, b; };
struct Net16 { CEp ce[63]; };

constexpr int oem_merge(CEp* out, int c, int lo, int n, int r) {
    const int m = r * 2;
    if (m < n) {
        c = oem_merge(out, c, lo, n, m);
        c = oem_merge(out, c, lo + r, n, m);
        for (int i = lo + r; i + r < lo + n; i += m) {
            out[c].a = (signed char)i; out[c].b = (signed char)(i + r); ++c;
        }
    } else {
        out[c].a = (signed char)lo; out[c].b = (signed char)(lo + r); ++c;
    }
    return c;
}
constexpr int oem_sort(CEp* out, int c, int lo, int n) {
    if (n > 1) {
        const int m = n / 2;
        c = oem_sort(out, c, lo, m);
        c = oem_sort(out, c, lo + m, m);
        c = oem_merge(out, c, lo, n, 1);
    }
    return c;
}
constexpr Net16 make_net16() {
    Net16 net{};
    (void)oem_sort(net.ce, 0, 0, 16);
    return net;
}
constexpr Net16 NET16 = make_net16();

// w-index -> v-index map for the final bitonic merge
constexpr int WMAP(int i) { return i < 16 ? i : 47 - i; }

#define PKMIN(d, s0, s1) asm("v_pk_min_f16 %0, %1, %2" : "=v"(d) : "v"(s0), "v"(s1))
#define PKMAX(d, s0, s1) asm("v_pk_max_f16 %0, %1, %2" : "=v"(d) : "v"(s0), "v"(s1))

#define CE1(arr, p, q) do { v2h n_, x_;                                  \
    PKMIN(n_, arr[p], arr[q]); PKMAX(x_, arr[p], arr[q]);                \
    arr[p] = n_; arr[q] = x_; } while (0)

// Sort one channel-pair's 32 values; on return the middle-4 SET (ranks
// 14..17) is in v[14], v[15], v[30], v[31] (internal order arbitrary).
// Network: 2 x Batcher-16 (63 CE) + bitonic merge pruned to middle 4 (44 CE).
__device__ __forceinline__ void sort_mid4(v2h (&v)[KK]) {
    #pragma unroll
    for (int t = 0; t < 63; ++t) CE1(v, NET16.ce[t].a, NET16.ce[t].b);
    #pragma unroll
    for (int t = 0; t < 63; ++t) CE1(v, NET16.ce[t].a + 16, NET16.ce[t].b + 16);
    #pragma unroll
    for (int i = 0; i < 16; ++i) CE1(v, WMAP(i), WMAP(i + 16));               // j=16
    #pragma unroll
    for (int i = 0; i < 8; ++i) { CE1(v, WMAP(i), WMAP(i + 8));               // j=8
                                  CE1(v, WMAP(i + 16), WMAP(i + 24)); }
    #pragma unroll
    for (int i = 8; i < 12; ++i) { CE1(v, WMAP(i), WMAP(i + 4));              // j=4
                                   CE1(v, WMAP(i + 8), WMAP(i + 12)); }
    CE1(v, WMAP(12), WMAP(14)); CE1(v, WMAP(13), WMAP(15));                   // j=2
    CE1(v, WMAP(16), WMAP(18)); CE1(v, WMAP(17), WMAP(19));
}

#define SOFF_STRIDE 33   // padded: wave reads 16 rows' entries -> 16 banks

// ---------------------------------------------------------------------------
// Kernel 2: slab-partitioned trimmed mean.
// Grid = 8 groups x 1563 row-blocks; g = blockIdx & 7 keeps all blocks of a
// slab on one XCD (round-robin dispatch) -> slab (3.2 MB) is L2-resident.
// Block = 256 threads = 64 rows x 4 threads (4 f16 channels each).
// waves_per_eu(4,4) pins VGPR budget at 128 so the 64 live v2h stay in
// architectural VGPRs (r5: compiler chased 8 waves/EU -> AGPR round-trips).
// ---------------------------------------------------------------------------
__global__ __attribute__((amdgpu_waves_per_eu(4, 4))) __launch_bounds__(256)
void trimmed_mean_kernel(const _Float16* __restrict__ hs, const int* __restrict__ nbrs,
                         float* __restrict__ out) {
    __shared__ int s_off[64 * SOFF_STRIDE];   // byte offsets into slab

    const int tid = threadIdx.x;
    const int g = blockIdx.x & 7;                   // channel group / XCD slot
    const int row_base = (blockIdx.x >> 3) * 64;

    // load 64 rows x 32 idx = 2048 ints, pre-scaled to slab byte offsets
    {
        const int base = row_base * KK;
        #pragma unroll
        for (int t = 0; t < 8; ++t) {
            const int i = tid + 256 * t;            // 0..2047
            const int gi = base + i;
            const int idx = (gi < NN * KK) ? nbrs[gi] : 0;
            s_off[(i >> 5) * SOFF_STRIDE + (i & 31)] = idx * 32;  // 16 ch * 2 B
        }
    }
    __syncthreads();

    const int rsub = tid >> 2;        // 0..63 row within block
    const int cq   = tid & 3;         // 4-channel quad within the 16-ch group
    const int row  = row_base + rsub;

    const char* slab = (const char*)hs + (size_t)g * (SLAB_HALVES * 2) + cq * 8;
    const int* my_off = &s_off[rsub * SOFF_STRIDE];

    v2h va[KK];   // channels 16g+4cq+0,1
    v2h vb[KK];   // channels 16g+4cq+2,3

    // all 32 gathers in flight up front (latency hiding)
    #pragma unroll
    for (int k = 0; k < KK; ++k) {
        const uint2 u = *(const uint2*)(slab + my_off[k]);
        va[k] = __builtin_bit_cast(v2h, u.x);
        vb[k] = __builtin_bit_cast(v2h, u.y);
    }

    // sequential sorts: pair A fully, emit floats, then pair B
    sort_mid4(va);
    const float oa0 = ((float)va[14].x + (float)va[15].x +
                       (float)va[30].x + (float)va[31].x) * 0.25f;
    const float oa1 = ((float)va[14].y + (float)va[15].y +
                       (float)va[30].y + (float)va[31].y) * 0.25f;

    sort_mid4(vb);
    const float ob0 = ((float)vb[14].x + (float)vb[15].x +
                       (float)vb[30].x + (float)vb[31].x) * 0.25f;
    const float ob1 = ((float)vb[14].y + (float)vb[15].y +
                       (float)vb[30].y + (float)vb[31].y) * 0.25f;

    if (row < NN) {
        float4 o = make_float4(oa0, oa1, ob0, ob1);
        *(float4*)(out + (size_t)row * DD + g * 16 + cq * 4) = o;
    }
}

extern "C" void kernel_launch(void* const* d_in, const int* in_sizes, int n_in,
                              void* d_out, int out_size, void* d_ws, size_t ws_size,
                              hipStream_t stream) {
    const float* x    = (const float*)d_in[0];   // (N, 128) fp32
    const float* W    = (const float*)d_in[1];   // (128, 128) fp32
    const int*   nbrs = (const int*)d_in[2];     // (N, 32) int32
    float*       out  = (float*)d_out;           // (N, 128) fp32
    _Float16*    hs   = (_Float16*)d_ws;         // 8 slabs x 3.2 MB = 25.6 MB

    (void)in_sizes; (void)n_in; (void)out_size; (void)ws_size;

    gemm_mfma_kernel<<<(NN + 127) / 128, 256, 0, stream>>>(x, W, hs);    // 782 blocks
    trimmed_mean_kernel<<<8 * ((NN + 63) / 64), 256, 0, stream>>>(hs, nbrs, out); // 12504
}

// Round 7
// 233.287 us; speedup vs baseline: 1.1291x; 1.1291x over previous
//
#include <hip/hip_runtime.h>
#include <hip/hip_fp16.h>

// Problem constants (from reference)
#define NN 100000
#define KK 32
#define DD 128
// remove = floor(32*0.45) = 14 -> keep sorted ranks [14,18), mean of 4

typedef _Float16 v8h __attribute__((ext_vector_type(8)));
typedef _Float16 v4h __attribute__((ext_vector_type(4)));
typedef _Float16 v2h __attribute__((ext_vector_type(2)));
typedef float    v4f __attribute__((ext_vector_type(4)));

#define LDH 136   // padded LDS row stride in f16 (128 + 8)

// h scratch layout: 8 channel-group slabs, hs[g][n][16] f16.
// slab g holds channels [16g, 16g+16); slab size = NN*32 B = 3.2 MB < 4 MiB L2.
#define SLAB_HALVES ((size_t)NN * 16)

// ---------------------------------------------------------------------------
// Kernel 1: h = x @ W^T in f16 via MFMA 16x16x32, writing slab layout.
// (unchanged)
// ---------------------------------------------------------------------------
__global__ __launch_bounds__(256)
void gemm_mfma_kernel(const float* __restrict__ x, const float* __restrict__ W,
                      _Float16* __restrict__ hs) {
    __shared__ _Float16 w_lds[DD * LDH];
    __shared__ _Float16 x_lds[128 * LDH];

    const int tid = threadIdx.x;
    const int block_row = blockIdx.x * 128;

    {
        const float4* ws = (const float4*)W;
        #pragma unroll
        for (int t = 0; t < 16; ++t) {
            const int fi = tid + 256 * t;
            const int r = fi >> 5, c4 = fi & 31;
            const float4 f = ws[fi];
            v4h p = { (_Float16)f.x, (_Float16)f.y, (_Float16)f.z, (_Float16)f.w };
            *(v4h*)&w_lds[r * LDH + c4 * 4] = p;
        }
    }
    {
        const float4* xs = (const float4*)x;
        #pragma unroll
        for (int t = 0; t < 16; ++t) {
            const int fi = tid + 256 * t;
            const int r = fi >> 5, c4 = fi & 31;
            const int gr = block_row + r;
            float4 f = make_float4(0.f, 0.f, 0.f, 0.f);
            if (gr < NN) f = xs[(size_t)gr * 32 + c4];
            v4h p = { (_Float16)f.x, (_Float16)f.y, (_Float16)f.z, (_Float16)f.w };
            *(v4h*)&x_lds[r * LDH + c4 * 4] = p;
        }
    }
    __syncthreads();

    const int wv   = tid >> 6;
    const int lane = tid & 63;
    const int m    = lane & 15;
    const int quad = lane >> 4;

    const v4f zero = {0.f, 0.f, 0.f, 0.f};
    v4f acc[2][8];
    #pragma unroll
    for (int nt = 0; nt < 2; ++nt)
        #pragma unroll
        for (int ot = 0; ot < 8; ++ot) acc[nt][ot] = zero;

    #pragma unroll
    for (int ks = 0; ks < 4; ++ks) {
        const int kb = ks * 32 + quad * 8;
        const v8h xf0 = *(const v8h*)&x_lds[(wv * 32 + m) * LDH + kb];
        const v8h xf1 = *(const v8h*)&x_lds[(wv * 32 + 16 + m) * LDH + kb];
        #pragma unroll
        for (int ot = 0; ot < 8; ++ot) {
            const v8h wf = *(const v8h*)&w_lds[(ot * 16 + m) * LDH + kb];
            acc[0][ot] = __builtin_amdgcn_mfma_f32_16x16x32_f16(wf, xf0, acc[0][ot], 0, 0, 0);
            acc[1][ot] = __builtin_amdgcn_mfma_f32_16x16x32_f16(wf, xf1, acc[1][ot], 0, 0, 0);
        }
    }

    #pragma unroll
    for (int nt = 0; nt < 2; ++nt) {
        const int xr = block_row + wv * 32 + nt * 16 + m;
        if (xr < NN) {
            #pragma unroll
            for (int ot = 0; ot < 8; ++ot) {
                const v4f a = acc[nt][ot];
                v4h p = { (_Float16)a.x, (_Float16)a.y, (_Float16)a.z, (_Float16)a.w };
                *(v4h*)&hs[(size_t)ot * SLAB_HALVES + (size_t)xr * 16 + quad * 4] = p;
            }
        }
    }
}

// ---------------------------------------------------------------------------
// Compile-time Batcher odd-even mergesort network for 16 elements (63 CEs).
// ---------------------------------------------------------------------------
struct CEp { signed char a, b; };
struct Net16 { CEp ce[63]; };

constexpr int oem_merge(CEp* out, int c, int lo, int n, int r) {
    const int m = r * 2;
    if (m < n) {
        c = oem_merge(out, c, lo, n, m);
        c = oem_merge(out, c, lo + r, n, m);
        for (int i = lo + r; i + r < lo + n; i += m) {
            out[c].a = (signed char)i; out[c].b = (signed char)(i + r); ++c;
        }
    } else {
        out[c].a = (signed char)lo; out[c].b = (signed char)(lo + r); ++c;
    }
    return c;
}
constexpr int oem_sort(CEp* out, int c, int lo, int n) {
    if (n > 1) {
        const int m = n / 2;
        c = oem_sort(out, c, lo, m);
        c = oem_sort(out, c, lo + m, m);
        c = oem_merge(out, c, lo, n, 1);
    }
    return c;
}
constexpr Net16 make_net16() {
    Net16 net{};
    (void)oem_sort(net.ce, 0, 0, 16);
    return net;
}
constexpr Net16 NET16 = make_net16();

// w-index -> v-index map for the final bitonic merge
constexpr int WMAP(int i) { return i < 16 ? i : 47 - i; }

#define PKMIN(d, s0, s1) asm("v_pk_min_f16 %0, %1, %2" : "=v"(d) : "v"(s0), "v"(s1))
#define PKMAX(d, s0, s1) asm("v_pk_max_f16 %0, %1, %2" : "=v"(d) : "v"(s0), "v"(s1))

#define CE1(arr, p, q) do { v2h n_, x_;                                  \
    PKMIN(n_, arr[p], arr[q]); PKMAX(x_, arr[p], arr[q]);                \
    arr[p] = n_; arr[q] = x_; } while (0)

// Sort one channel-pair's 32 values; on return the middle-4 SET (ranks
// 14..17) is in v[14], v[15], v[30], v[31] (internal order arbitrary).
// Network: 2 x Batcher-16 (63 CE) + bitonic merge pruned to middle 4 (44 CE).
__device__ __forceinline__ void sort_mid4(v2h (&v)[KK]) {
    #pragma unroll
    for (int t = 0; t < 63; ++t) CE1(v, NET16.ce[t].a, NET16.ce[t].b);
    #pragma unroll
    for (int t = 0; t < 63; ++t) CE1(v, NET16.ce[t].a + 16, NET16.ce[t].b + 16);
    #pragma unroll
    for (int i = 0; i < 16; ++i) CE1(v, WMAP(i), WMAP(i + 16));               // j=16
    #pragma unroll
    for (int i = 0; i < 8; ++i) { CE1(v, WMAP(i), WMAP(i + 8));               // j=8
                                  CE1(v, WMAP(i + 16), WMAP(i + 24)); }
    #pragma unroll
    for (int i = 8; i < 12; ++i) { CE1(v, WMAP(i), WMAP(i + 4));              // j=4
                                   CE1(v, WMAP(i + 8), WMAP(i + 12)); }
    CE1(v, WMAP(12), WMAP(14)); CE1(v, WMAP(13), WMAP(15));                   // j=2
    CE1(v, WMAP(16), WMAP(18)); CE1(v, WMAP(17), WMAP(19));
}

#define SOFF_STRIDE 33   // pad so 8 concurrent rows hit 8 distinct banks

// ---------------------------------------------------------------------------
// Kernel 2: slab-partitioned trimmed mean, 2 channels/thread.
// Grid = 8 slabs x 3125 row-blocks; g = blockIdx & 7 -> slab stays on one XCD.
// Block = 256 threads = 32 rows x 8 lanes; each lane owns 1 dword (2 f16 ch).
// A wave covers 8 rows; its 8-lane row groups coalesce into one 32 B request
// per (row, neighbor). Live set ~45 VGPR -> fits 8 waves/EU, no AGPR split.
// ---------------------------------------------------------------------------
__global__ __launch_bounds__(256)
void trimmed_mean_kernel(const _Float16* __restrict__ hs, const int* __restrict__ nbrs,
                         float* __restrict__ out) {
    __shared__ int s_off[32 * SOFF_STRIDE];   // byte offsets into slab, 4.2 KB

    const int tid = threadIdx.x;
    const int g = blockIdx.x & 7;                   // channel group / XCD slot
    const int row_base = (blockIdx.x >> 3) * 32;

    // stage 32 rows x 32 idx = 1024 ints, pre-scaled to slab byte offsets
    {
        const int base = row_base * KK;
        #pragma unroll
        for (int t = 0; t < 4; ++t) {
            const int i = tid + 256 * t;            // 0..1023, always in range
            const int idx = nbrs[base + i];
            s_off[(i >> 5) * SOFF_STRIDE + (i & 31)] = idx * 32;  // 16 ch * 2 B
        }
    }
    __syncthreads();

    const int rsub = tid >> 3;        // 0..31 row within block
    const int c    = tid & 7;         // dword within the 16-ch group
    const int row  = row_base + rsub;

    const char* slab = (const char*)hs + (size_t)g * (SLAB_HALVES * 2) + c * 4;
    const int* my_off = &s_off[rsub * SOFF_STRIDE];

    v2h v[KK];   // channels 16g + 2c, 16g + 2c + 1
    #pragma unroll
    for (int k = 0; k < KK; ++k) {
        const unsigned u = *(const unsigned*)(slab + my_off[k]);
        v[k] = __builtin_bit_cast(v2h, u);
    }

    sort_mid4(v);

    const float o0 = ((float)v[14].x + (float)v[15].x +
                      (float)v[30].x + (float)v[31].x) * 0.25f;
    const float o1 = ((float)v[14].y + (float)v[15].y +
                      (float)v[30].y + (float)v[31].y) * 0.25f;

    // lanes of a row write 16 consecutive floats (64 B) -> coalesced
    *(float2*)(out + (size_t)row * DD + g * 16 + c * 2) = make_float2(o0, o1);
}

extern "C" void kernel_launch(void* const* d_in, const int* in_sizes, int n_in,
                              void* d_out, int out_size, void* d_ws, size_t ws_size,
                              hipStream_t stream) {
    const float* x    = (const float*)d_in[0];   // (N, 128) fp32
    const float* W    = (const float*)d_in[1];   // (128, 128) fp32
    const int*   nbrs = (const int*)d_in[2];     // (N, 32) int32
    float*       out  = (float*)d_out;           // (N, 128) fp32
    _Float16*    hs   = (_Float16*)d_ws;         // 8 slabs x 3.2 MB = 25.6 MB

    (void)in_sizes; (void)n_in; (void)out_size; (void)ws_size;

    gemm_mfma_kernel<<<(NN + 127) / 128, 256, 0, stream>>>(x, W, hs);      // 782 blocks
    // 8 slabs x (100000/32 = 3125 exactly) = 25000 blocks
    trimmed_mean_kernel<<<25000, 256, 0, stream>>>(hs, nbrs, out);
}